// Round 2
// 3186.849 us; speedup vs baseline: 1.1883x; 1.1883x over previous
//
#include <hip/hip_runtime.h>
#include <cstdint>
#include <cstddef>

#define NEGV -1000000000.0f

// ---------- fast device math (fp32, argmax-safe) ----------
__device__ __forceinline__ float fsigm(float x) {
  return 1.0f / (1.0f + __expf(-x));
}
__device__ __forceinline__ float ftanh(float x) {
  x = fminf(x, 30.0f);
  const float e = __expf(2.0f * x);
  return (e - 1.0f) / (e + 1.0f);
}

// ---------------------------------------------------------------------------
// Fused setup GEMM: both context projections in one pass (shared A reads).
// A[32768][256] fp32 (context natural layout [l*512+b][h]),
// W2[512][256] = rows {Wrg | Wrp}, b2[512] = {brg | brp}.
// Outputs fp32 [32768][256] in natural layout.
// BM=128, BN=64 (x2 outputs), BK=16, 256 threads, micro 8m x 4n x 2s.
// Per-output k-accumulation order identical to the round-0 gemm (k ascending).
// ---------------------------------------------------------------------------
__global__ __launch_bounds__(256, 2) void gemm2_k(
    const float* __restrict__ A0, const float* __restrict__ W2,
    const float* __restrict__ b2, float* __restrict__ Cg,
    float* __restrict__ Cp)
{
  __shared__ float As[16][136];     // [k][m]
  __shared__ float Ws[2][16][72];   // [s][k][n]
  const int bn = blockIdx.x << 6;   // 0..192
  const int bm = blockIdx.y << 7;   // 0..32640
  const int t  = threadIdx.x;
  const int ty = t >> 4, tx = t & 15;
  const int ar = t >> 1, ac = (t & 1) << 3;   // A staging: 2 float4
  const int wr = t >> 2, wc = (t & 3) << 2;   // W staging: 1 float4 per s
  const float* arow = A0 + (size_t)(bm + ar) * 256 + ac;
  float acc[2][8][4] = {};
  for (int k0 = 0; k0 < 256; k0 += 16) {
    const float4 a0 = *(const float4*)(arow + k0);
    const float4 a1 = *(const float4*)(arow + k0 + 4);
    As[ac + 0][ar] = a0.x; As[ac + 1][ar] = a0.y; As[ac + 2][ar] = a0.z; As[ac + 3][ar] = a0.w;
    As[ac + 4][ar] = a1.x; As[ac + 5][ar] = a1.y; As[ac + 6][ar] = a1.z; As[ac + 7][ar] = a1.w;
#pragma unroll
    for (int s = 0; s < 2; ++s) {
      const float4 wv = *(const float4*)(W2 + (size_t)(s * 256 + bn + wr) * 256 + k0 + wc);
      Ws[s][wc + 0][wr] = wv.x; Ws[s][wc + 1][wr] = wv.y;
      Ws[s][wc + 2][wr] = wv.z; Ws[s][wc + 3][wr] = wv.w;
    }
    __syncthreads();
#pragma unroll
    for (int k = 0; k < 16; ++k) {
      const float4 a0v = *(const float4*)&As[k][ty << 3];
      const float4 a1v = *(const float4*)&As[k][(ty << 3) + 4];
      const float am[8] = {a0v.x, a0v.y, a0v.z, a0v.w, a1v.x, a1v.y, a1v.z, a1v.w};
#pragma unroll
      for (int s = 0; s < 2; ++s) {
        const float4 wv = *(const float4*)&Ws[s][k][tx << 2];
#pragma unroll
        for (int i = 0; i < 8; ++i) {
          acc[s][i][0] += am[i] * wv.x;
          acc[s][i][1] += am[i] * wv.y;
          acc[s][i][2] += am[i] * wv.z;
          acc[s][i][3] += am[i] * wv.w;
        }
      }
    }
    __syncthreads();
  }
  const int cn = bn + (tx << 2);
  const float4 bg = *(const float4*)(b2 + cn);
  const float4 bp = *(const float4*)(b2 + 256 + cn);
#pragma unroll
  for (int i = 0; i < 8; ++i) {
    const size_t row = ((size_t)(bm + (ty << 3) + i)) << 8;
    float4 o;
    o.x = acc[0][i][0] + bg.x; o.y = acc[0][i][1] + bg.y;
    o.z = acc[0][i][2] + bg.z; o.w = acc[0][i][3] + bg.w;
    *(float4*)(Cg + row + cn) = o;
    o.x = acc[1][i][0] + bp.x; o.y = acc[1][i][1] + bp.y;
    o.z = acc[1][i][2] + bp.z; o.w = acc[1][i][3] + bp.w;
    *(float4*)(Cp + row + cn) = o;
  }
}

// ---------------------------------------------------------------------------
// gates GEMM (M=512, N=1024 interleaved i,f,g,o per unit, K=512 = [x|h])
// + fused LSTM epilogue. BM=16, BN=64, BK=32 -> 512 blocks (2/CU).
// ---------------------------------------------------------------------------
__global__ __launch_bounds__(256) void gates_lstm_k(
    const float* __restrict__ x, const float* __restrict__ hin,
    const float* __restrict__ Wcat, const float* __restrict__ bcat,
    const float* __restrict__ cin, float* __restrict__ cnew,
    float* __restrict__ hnew)
{
  __shared__ __align__(16) float As[16][36];   // [m][k]
  __shared__ __align__(16) float Ws[32][68];   // [k][n]
  const int bn = blockIdx.x << 6;
  const int bm = blockIdx.y << 4;
  const int t  = threadIdx.x;
  const int ty = t >> 4, tx = t & 15;
  const int ar = t >> 4, ak = (t & 15) << 1;   // A staging: one float2
  const int wr = t >> 2, wk = (t & 3) << 3;    // W staging: two float4
  const float* wrow = Wcat + ((size_t)(bn + wr) << 9);
  const int arow = bm + ar;
  float acc0 = 0.f, acc1 = 0.f, acc2 = 0.f, acc3 = 0.f;
  for (int k0 = 0; k0 < 512; k0 += 32) {
    const int kk = k0 + ak;
    float2 av;
    if (kk < 256) av = *(const float2*)(x   + ((size_t)arow << 8) + kk);
    else          av = *(const float2*)(hin + ((size_t)arow << 8) + (kk - 256));
    const float4 w0 = *(const float4*)(wrow + k0 + wk);
    const float4 w1 = *(const float4*)(wrow + k0 + wk + 4);
    *(float2*)&As[ar][ak] = av;
    Ws[wk + 0][wr] = w0.x; Ws[wk + 1][wr] = w0.y; Ws[wk + 2][wr] = w0.z; Ws[wk + 3][wr] = w0.w;
    Ws[wk + 4][wr] = w1.x; Ws[wk + 5][wr] = w1.y; Ws[wk + 6][wr] = w1.z; Ws[wk + 7][wr] = w1.w;
    __syncthreads();
#pragma unroll
    for (int k = 0; k < 32; ++k) {
      const float a  = As[ty][k];
      const float4 w = *(const float4*)&Ws[k][tx << 2];
      acc0 += a * w.x; acc1 += a * w.y; acc2 += a * w.z; acc3 += a * w.w;
    }
    __syncthreads();
  }
  const float4 bb = *(const float4*)(bcat + bn + (tx << 2));
  const int jc = (bn >> 2) + tx;
  const int m  = bm + ty;
  const float ig = fsigm(acc0 + bb.x);
  const float fg = fsigm(acc1 + bb.y);
  const float gg = ftanh(acc2 + bb.z);
  const float og = fsigm(acc3 + bb.w);
  const float c  = fg * cin[(m << 8) + jc] + ig * gg;
  const float h  = og * ftanh(c);
  cnew[(m << 8) + jc] = c;
  hnew[(m << 8) + jc] = h;
}

// ---------------------------------------------------------------------------
// Fused per-step attention, all fp32. One block of 512 threads per batch b.
// gl accumulated ONLINE (flash-style) during scores_g pass -> no Eg2 stream.
// qp = bqp + Wqp @ gl via L2-resident packed matvec.
// ---------------------------------------------------------------------------
__global__ __launch_bounds__(512) void step_attn_k(
    const float* __restrict__ h, const float* __restrict__ e2g,
    const float* __restrict__ e2p, const float* __restrict__ Wq1T4,
    const float* __restrict__ Wqp4, const float* __restrict__ qcour,
    const float* __restrict__ bqp, const float* __restrict__ vg,
    const float* __restrict__ vp, unsigned long long* __restrict__ mask,
    int* __restrict__ idxb, const float* __restrict__ emb,
    float* __restrict__ out_logp, float* __restrict__ out_sel,
    float* __restrict__ xb, int t)
{
  const int b = blockIdx.x, tid = threadIdx.x;
  __shared__ __align__(16) float hs[256], qgs[256], qps[256], gls[256];
  __shared__ __align__(16) float vgs[256], vps[256];
  __shared__ __align__(16) float glp[8][256];
  __shared__ __align__(16) float part[512];
  __shared__ float us[64], mxs[8], zws[8];
  __shared__ unsigned long long ms;
  __shared__ int bsel;
  if (tid < 256) {
    hs[tid]  = h[(b << 8) + tid];
    vgs[tid] = vg[tid];
    vps[tid] = vp[tid];
  }
  if (tid == 0) {
    unsigned long long m = mask[b];
    if (t > 0) {
      int s = idxb[b]; if (s < 0) s = 0;
      m |= (1ULL << s);
      if (m == ~0ULL) m &= ~(1ULL << 63);
      mask[b] = m;
    }
    ms = m;
  }
  __syncthreads();
  const unsigned long long mm = ms;
  const int w = tid >> 6, lane = tid & 63;
  const int o = tid & 255, kh = tid >> 8;

  // phase 0: qg[o] = qcour[b,o] + sum_k Wq1[o][k] * h[b,k]  (split-k x2)
  {
    float acc = (kh == 0) ? qcour[(b << 8) + o] : 0.f;
    const float4* wp = (const float4*)Wq1T4 + o;
    const int kc0 = kh << 5;
#pragma unroll 8
    for (int kc = kc0; kc < kc0 + 32; ++kc) {
      const float4 wv = wp[kc << 8];
      const float4 h4 = *(const float4*)&hs[kc << 2];
      acc += wv.x * h4.x + wv.y * h4.y + wv.z * h4.z + wv.w * h4.w;
    }
    part[tid] = acc;
  }
  __syncthreads();
  if (tid < 256) qgs[tid] = part[tid] + part[tid + 256];
  __syncthreads();

  // scores_g over e2g + online-softmax accumulation of gl (8 l per wave)
  {
    const float4 q4 = *(const float4*)&qgs[lane << 2];
    const float4 v4 = *(const float4*)&vgs[lane << 2];
    const float* ebase = e2g + ((size_t)b << 8) + (lane << 2);
    float g0 = 0.f, g1 = 0.f, g2 = 0.f, g3 = 0.f;
    float mxw = -1e30f, zw = 0.f;
    for (int li = 0; li < 8; ++li) {
      const int l = (w << 3) + li;
      const float4 e4 = *(const float4*)(ebase + ((size_t)l << 17));
      float s = v4.x * ftanh(q4.x + e4.x) + v4.y * ftanh(q4.y + e4.y)
              + v4.z * ftanh(q4.z + e4.z) + v4.w * ftanh(q4.w + e4.w);
#pragma unroll
      for (int off = 32; off; off >>= 1) s += __shfl_xor(s, off, 64);
      if (!((mm >> l) & 1ULL)) {          // wave-uniform branch
        const float nm   = fmaxf(mxw, s);
        const float corr = __expf(mxw - nm);   // 0 on first hit (mxw=-1e30)
        const float wl   = __expf(s - nm);
        zw = zw * corr + wl;
        g0 = g0 * corr + wl * e4.x; g1 = g1 * corr + wl * e4.y;
        g2 = g2 * corr + wl * e4.z; g3 = g3 * corr + wl * e4.w;
        mxw = nm;
      }
    }
    glp[w][(lane << 2) + 0] = g0; glp[w][(lane << 2) + 1] = g1;
    glp[w][(lane << 2) + 2] = g2; glp[w][(lane << 2) + 3] = g3;
    if (lane == 0) { mxs[w] = mxw; zws[w] = zw; }
  }
  __syncthreads();
  if (tid < 256) {
    float MX = mxs[0];
#pragma unroll
    for (int ww = 1; ww < 8; ++ww) MX = fmaxf(MX, mxs[ww]);
    float Z = 0.f, go = 0.f;
#pragma unroll
    for (int ww = 0; ww < 8; ++ww) {
      const float sc = __expf(mxs[ww] - MX);   // 0 for all-masked waves
      Z  += sc * zws[ww];
      go += sc * glp[ww][tid];
    }
    gls[tid] = go / Z;
  }
  __syncthreads();

  // qp[o] = bqp[o] + sum_k Wqp[o][k] * gl[k]  (split-k x2)
  {
    float acc = (kh == 0) ? bqp[o] : 0.f;
    const float4* wp = (const float4*)Wqp4 + o;
    const int kc0 = kh << 5;
#pragma unroll 8
    for (int kc = kc0; kc < kc0 + 32; ++kc) {
      const float4 wv = wp[kc << 8];
      const float4 h4 = *(const float4*)&gls[kc << 2];
      acc += wv.x * h4.x + wv.y * h4.y + wv.z * h4.z + wv.w * h4.w;
    }
    part[tid] = acc;
  }
  __syncthreads();
  if (tid < 256) qps[tid] = part[tid] + part[tid + 256];
  __syncthreads();

  // scores_p over e2p, 10*tanh, mask -> us
  {
    const float4 q4 = *(const float4*)&qps[lane << 2];
    const float4 v4 = *(const float4*)&vps[lane << 2];
    const float* ebase = e2p + ((size_t)b << 8) + (lane << 2);
    for (int li = 0; li < 8; ++li) {
      const int l = (w << 3) + li;
      const float4 e4 = *(const float4*)(ebase + ((size_t)l << 17));
      float s = v4.x * ftanh(q4.x + e4.x) + v4.y * ftanh(q4.y + e4.y)
              + v4.z * ftanh(q4.z + e4.z) + v4.w * ftanh(q4.w + e4.w);
#pragma unroll
      for (int off = 32; off; off >>= 1) s += __shfl_xor(s, off, 64);
      if (lane == 0) us[l] = ((mm >> l) & 1ULL) ? NEGV : 10.0f * ftanh(s);
    }
  }
  __syncthreads();
  if (tid < 64) {
    const float xv = us[tid];
    float mx = xv;
#pragma unroll
    for (int off = 32; off; off >>= 1) mx = fmaxf(mx, __shfl_xor(mx, off, 64));
    const float sh = xv - mx;
    const float ev = __expf(sh);
    float sum = ev;
#pragma unroll
    for (int off = 32; off; off >>= 1) sum += __shfl_xor(sum, off, 64);
    const float lp = sh - __logf(sum);
    out_logp[((size_t)b << 12) + (t << 6) + tid] = lp;
    float bv = lp; int bi = tid;
#pragma unroll
    for (int off = 32; off; off >>= 1) {
      const float ov = __shfl_xor(bv, off, 64);
      const int   oi = __shfl_xor(bi, off, 64);
      if (ov > bv || (ov == bv && oi < bi)) { bv = ov; bi = oi; }
    }
    if (tid == 0) { idxb[b] = bi; out_sel[(b << 6) + t] = (float)bi; bsel = bi; }
  }
  __syncthreads();
  if (tid < 256) xb[(b << 8) + tid] = emb[(((size_t)(bsel << 9) + b) << 8) + tid];
}

// ---------------------------------------------------------------------------
// setup kernels
// ---------------------------------------------------------------------------
__global__ __launch_bounds__(256) void init_k(
    const float* __restrict__ dec, const float* __restrict__ h0,
    const float* __restrict__ c0, float* __restrict__ xb,
    float* __restrict__ hb, float* __restrict__ cb,
    unsigned long long* __restrict__ mask, int* __restrict__ idxb)
{
  const int i = blockIdx.x * 256 + threadIdx.x;
  xb[i] = dec[i]; hb[i] = h0[i]; cb[i] = c0[i];
  if (i < 512) { mask[i] = 0ULL; idxb[i] = -1; }
}

// Wcat[n][k], n=4*j+p interleaved (p in {i,f,g,o}), k = [x-part | h-part]
__global__ __launch_bounds__(256) void prep_wcat_k(
    const float* __restrict__ Wih, const float* __restrict__ Whh,
    const float* __restrict__ bih, const float* __restrict__ bhh,
    float* __restrict__ Wcat, float* __restrict__ bcat)
{
  const int id = blockIdx.x * 256 + threadIdx.x;
  const int n = id >> 9, k = id & 511;
  const int r = ((n & 3) << 8) + (n >> 2);
  Wcat[id] = (k < 256) ? Wih[(r << 8) + k] : Whh[(r << 8) + (k - 256)];
  if (id < 1024) {
    const int rr = ((id & 3) << 8) + (id >> 2);
    bcat[id] = bih[rr] + bhh[rr];
  }
}

// Wfused = Wq_g @ Wm (256x320), bfused = Wq_g @ bm + bq_g
__global__ __launch_bounds__(256) void prep_wfused_k(
    const float* __restrict__ Wqg, const float* __restrict__ Wm,
    const float* __restrict__ bm, const float* __restrict__ bqg,
    float* __restrict__ Wf, float* __restrict__ bf)
{
  const int id = blockIdx.x * 256 + threadIdx.x;  // 81920
  const int o = id / 320, j = id % 320;
  float acc = 0.f;
  for (int tt = 0; tt < 256; ++tt) acc += Wqg[(o << 8) + tt] * Wm[tt * 320 + j];
  Wf[id] = acc;
  if (id < 256) {
    float a2 = 0.f;
    for (int tt = 0; tt < 256; ++tt) a2 += Wqg[(id << 8) + tt] * bm[tt];
    bf[id] = a2 + bqg[id];
  }
}

// Wq1T4: packed transpose of Wfused[:, :256] for coalesced float4 matvec.
__global__ __launch_bounds__(256) void prep_wq1t4_k(
    const float* __restrict__ Wf, float* __restrict__ Wq1T4)
{
  const int id = blockIdx.x * 256 + threadIdx.x;  // 65536
  const int k = id >> 8, o = id & 255;
  Wq1T4[((k >> 2) << 10) + (o << 2) + (k & 3)] = Wf[o * 320 + k];
}

// Wqp4: packed transpose of raw Wqp for coalesced float4 matvec.
__global__ __launch_bounds__(256) void prep_wqp4_k(
    const float* __restrict__ Wqp, float* __restrict__ Wqp4)
{
  const int id = blockIdx.x * 256 + threadIdx.x;  // 65536
  const int k = id >> 8, o = id & 255;
  Wqp4[((k >> 2) << 10) + (o << 2) + (k & 3)] = Wqp[(o << 8) + k];
}

// qcour[b,o] = bfused[o] + sum_{k<64} Wfused[o][256+k] * cour[b][k]
__global__ __launch_bounds__(256) void prep_qcour_k(
    const float* __restrict__ Wf, const float* __restrict__ bf,
    const float* __restrict__ cour, float* __restrict__ qcour)
{
  const int b = blockIdx.x, o = threadIdx.x;
  __shared__ float cs[64];
  if (o < 64) cs[o] = cour[(b << 6) + o];
  __syncthreads();
  float acc = bf[o];
#pragma unroll 8
  for (int k = 0; k < 64; ++k) acc += Wf[o * 320 + 256 + k] * cs[k];
  qcour[(b << 8) + o] = acc;
}

// W2 rows 0..255 = Wrg, rows 256..511 = Wrp; b2 = {brg | brp}
__global__ __launch_bounds__(256) void prep_w2copy_k(
    const float* __restrict__ Wrg, const float* __restrict__ Wrp,
    const float* __restrict__ brg, const float* __restrict__ brp,
    float* __restrict__ W2, float* __restrict__ b2)
{
  const int id = blockIdx.x * 256 + threadIdx.x;   // 131072
  W2[id] = (id < 65536) ? Wrg[id] : Wrp[id - 65536];
  if (id < 256) b2[id] = brg[id];
  else if (id < 512) b2[id] = brp[id - 256];
}

// ---------------------------------------------------------------------------
extern "C" void kernel_launch(void* const* d_in, const int* in_sizes, int n_in,
                              void* d_out, int out_size, void* d_ws, size_t ws_size,
                              hipStream_t stream)
{
  const float* dec   = (const float*)d_in[0];
  const float* emb   = (const float*)d_in[1];
  const float* h0    = (const float*)d_in[2];
  const float* c0    = (const float*)d_in[3];
  const float* ctxin = (const float*)d_in[4];
  const float* cour  = (const float*)d_in[5];
  const float* Wih   = (const float*)d_in[7];
  const float* Whh   = (const float*)d_in[8];
  const float* bih   = (const float*)d_in[9];
  const float* bhh   = (const float*)d_in[10];
  const float* Wm    = (const float*)d_in[11];
  const float* bm    = (const float*)d_in[12];
  const float* Wqp   = (const float*)d_in[13];
  const float* bqp   = (const float*)d_in[14];
  const float* Wrp   = (const float*)d_in[15];
  const float* brp   = (const float*)d_in[16];
  const float* vp    = (const float*)d_in[17];
  const float* Wqg   = (const float*)d_in[18];
  const float* bqg   = (const float*)d_in[19];
  const float* Wrg   = (const float*)d_in[20];
  const float* brg   = (const float*)d_in[21];
  const float* vg    = (const float*)d_in[22];

  float* ws = (float*)d_ws;
  float* e2g    = ws + 0;         // 8388608
  float* e2p    = ws + 8388608;   // 8388608
  float* W2     = ws + 16777216;  // 131072
  float* b2     = ws + 16908288;  // 512
  float* Wcat   = ws + 16908800;  // 524288
  float* bcat   = ws + 17433088;  // 1024
  float* Wfused = ws + 17434112;  // 81920
  float* bfused = ws + 17516032;  // 256
  float* Wq1T4  = ws + 17516288;  // 65536
  float* Wqp4   = ws + 17581824;  // 65536
  float* qcour  = ws + 17647360;  // 131072
  float* hb0    = ws + 17778432;  // 131072
  float* hb1    = ws + 17909504;  // 131072
  float* cb0    = ws + 18040576;  // 131072
  float* cb1    = ws + 18171648;  // 131072
  float* xb     = ws + 18302720;  // 131072
  unsigned long long* maskb = (unsigned long long*)(ws + 18433792); // 512 u64
  int* idxb     = (int*)(ws + 18434816);                            // 512

  float* out_logp = (float*)d_out;            // [B][64][64]
  float* out_sel  = (float*)d_out + 2097152;  // [B][64]

  // ---- setup ----
  init_k<<<512, 256, 0, stream>>>(dec, h0, c0, xb, hb0, cb0, maskb, idxb);
  prep_wcat_k<<<2048, 256, 0, stream>>>(Wih, Whh, bih, bhh, Wcat, bcat);
  prep_wfused_k<<<320, 256, 0, stream>>>(Wqg, Wm, bm, bqg, Wfused, bfused);
  prep_wq1t4_k<<<256, 256, 0, stream>>>(Wfused, Wq1T4);
  prep_wqp4_k<<<256, 256, 0, stream>>>(Wqp, Wqp4);
  prep_qcour_k<<<512, 256, 0, stream>>>(Wfused, bfused, cour, qcour);
  prep_w2copy_k<<<512, 256, 0, stream>>>(Wrg, Wrp, brg, brp, W2, b2);
  gemm2_k<<<dim3(4, 256), 256, 0, stream>>>(ctxin, W2, b2, e2g, e2p);

  // ---- 64 sequential steps, 2 kernels each ----
  for (int t = 0; t < 64; ++t) {
    float* hcur = (t & 1) ? hb1 : hb0;
    float* hnew = (t & 1) ? hb0 : hb1;
    float* ccur = (t & 1) ? cb1 : cb0;
    float* cnew = (t & 1) ? cb0 : cb1;
    gates_lstm_k<<<dim3(16, 32), 256, 0, stream>>>(xb, hcur, Wcat, bcat,
                                                   ccur, cnew, hnew);
    step_attn_k<<<512, 512, 0, stream>>>(hnew, e2g, e2p, Wq1T4, Wqp4, qcour,
                                         bqp, vg, vp, maskb, idxb, emb,
                                         out_logp, out_sel, xb, t);
  }
}